// Round 8
// baseline (426.179 us; speedup 1.0000x reference)
//
#include <hip/hip_runtime.h>
#include <math.h>

namespace {

constexpr int NN  = 50000;
constexpr int CC  = 128;
constexpr int EMn = 1000000;
constexpr int ESn = 200000;
constexpr int MTILES = ESn / 32;   // 6250 tiles of 32 edges
constexpr int MGRID  = 512;        // persistent blocks, 2 per CU

using f32x4  = __attribute__((ext_vector_type(4))) float;
using short8 = __attribute__((ext_vector_type(8))) short;

__device__ __forceinline__ ushort f2bf(float f) {
  unsigned u = __float_as_uint(f);
  return (ushort)((u + 0x7fffu + ((u >> 16) & 1u)) >> 16);   // RNE
}
__device__ __forceinline__ unsigned cvtpk_bf16(float lo, float hi) {
  unsigned r;
  asm volatile("v_cvt_pk_bf16_f32 %0, %1, %2" : "=v"(r) : "v"(lo), "v"(hi));
  return r;
}
__device__ __forceinline__ float softplusf(float x) {
  return (x > 20.f) ? x : log1pf(expf(x));
}
__device__ __forceinline__ int sdot4i(unsigned a, unsigned b, int c) {
#if __has_builtin(__builtin_amdgcn_sdot4)
  return __builtin_amdgcn_sdot4((int)a, (int)b, c, false);
#else
  int r = c;
#pragma unroll
  for (int k = 0; k < 4; k++) {
    int xa = ((int)(a << (24 - 8 * k))) >> 24;
    int xb = ((int)(b << (24 - 8 * k))) >> 24;
    r += xa * xb;
  }
  return r;
#endif
}
__device__ __forceinline__ unsigned pack4(float a, float b, float c, float d) {
  int ia = __float2int_rn(a), ib = __float2int_rn(b);
  int ic = __float2int_rn(c), id = __float2int_rn(d);
  return (unsigned)(ia & 255) | ((unsigned)(ib & 255) << 8) |
         ((unsigned)(ic & 255) << 16) | ((unsigned)(id & 255) << 24);
}

// ---- K0: init scratch ----
__global__ void k_init(int* __restrict__ pidx, float* __restrict__ den,
                       float* __restrict__ num, float* __restrict__ cnt) {
  int i = blockIdx.x * blockDim.x + threadIdx.x;
  if (i < NN) { pidx[i] = -1; den[i] = 0.f; num[i] = 0.f; cnt[i] = 0.f; }
}

// ---- K_cvtq: per-row int8 quantization ----
__global__ void k_cvtq(const float* __restrict__ nodes, const float* __restrict__ nbrs,
                       char* __restrict__ qnodes, char* __restrict__ qunit,
                       char* __restrict__ qnbrs, float* __restrict__ nscale,
                       float* __restrict__ nbscale) {
  int row = blockIdx.x * 16 + (threadIdx.x >> 4);
  int li = threadIdx.x & 15;
  if (row >= 2 * NN) return;
  bool isn = row < NN;
  int r = isn ? row : row - NN;
  const float* src = (isn ? nodes : nbrs) + (size_t)r * CC;
  float4 x0 = *(const float4*)(src + li * 8);
  float4 x1 = *(const float4*)(src + li * 8 + 4);
  float v[8] = {x0.x, x0.y, x0.z, x0.w, x1.x, x1.y, x1.z, x1.w};
  float amax = 0.f, sq = 0.f;
#pragma unroll
  for (int j = 0; j < 8; j++) { amax = fmaxf(amax, fabsf(v[j])); sq += v[j] * v[j]; }
#pragma unroll
  for (int off = 1; off < 16; off <<= 1) {
    amax = fmaxf(amax, __shfl_xor(amax, off, 64));
    sq += __shfl_xor(sq, off, 64);
  }
  amax = fmaxf(amax, 1e-8f);
  float rs = 127.f / amax;
  uint2 p;
  p.x = pack4(v[0] * rs, v[1] * rs, v[2] * rs, v[3] * rs);
  p.y = pack4(v[4] * rs, v[5] * rs, v[6] * rs, v[7] * rs);
  if (isn) {
    *(uint2*)(qnodes + (size_t)r * CC + li * 8) = p;
    float ru = 127.f / fmaxf(sqrtf(sq), 1e-8f);
    uint2 pu;
    pu.x = pack4(v[0] * ru, v[1] * ru, v[2] * ru, v[3] * ru);
    pu.y = pack4(v[4] * ru, v[5] * ru, v[6] * ru, v[7] * ru);
    *(uint2*)(qunit + (size_t)r * CC + li * 8) = pu;
    if (li == 0) nscale[r] = amax / 127.f;
  } else {
    *(uint2*)(qnbrs + (size_t)r * CC + li * 8) = p;
    if (li == 0) nbscale[r] = amax / 127.f;
  }
}

// ---- K2: partner_index scatter-max ----
__global__ void k_partner(const int* __restrict__ ss, const int* __restrict__ sd,
                          int* __restrict__ pidx) {
  int i = blockIdx.x * blockDim.x + threadIdx.x;
  if (i >= 2 * ESn) return;
  int partner = (i < ESn) ? sd[i] : ss[i - ESn];
  atomicMax(&pidx[partner], i);
}

// ---- K_qnode: per-node query lookup ----
__global__ void k_qnode(const int* __restrict__ pidx, const int* __restrict__ ss,
                        const int* __restrict__ sd, int* __restrict__ qnode) {
  int n = blockIdx.x * blockDim.x + threadIdx.x;
  if (n >= NN) return;
  int pi = pidx[n];
  qnode[n] = (pi < 0) ? -1 : ((pi < ESn) ? ss[pi] : sd[pi - ESn]);
}

// ---- K3: cos + segmented sums, 8 lanes/edge ----
__global__ void k_cos8(const char* __restrict__ qunit, const int* __restrict__ qnode,
                       const int* __restrict__ ms, const int* __restrict__ md,
                       float* __restrict__ den, float* __restrict__ num,
                       float* __restrict__ cnt) {
  int t = threadIdx.x;
  int e = blockIdx.x * 32 + (t >> 3);
  int li = t & 7;
  int q = qnode[md[e]];
  if (q < 0) return;                        // uniform per 8-lane group
  int s = ms[e];
  uint4 a = ((const uint4*)(qunit + (size_t)q * CC))[li];
  uint4 b = ((const uint4*)(qunit + (size_t)s * CC))[li];
  int acc = 0;
  acc = sdot4i(a.x, b.x, acc); acc = sdot4i(a.y, b.y, acc);
  acc = sdot4i(a.z, b.z, acc); acc = sdot4i(a.w, b.w, acc);
#pragma unroll
  for (int off = 1; off < 8; off <<= 1) acc += __shfl_xor(acc, off, 64);
  if (li == 0) {
    float cv = (float)acc * (1.0f / (127.f * 127.f));
    float wv = expf(10.0f * cv);            // softmax shift-invariant: no max pass
    atomicAdd(&den[q], wv);
    atomicAdd(&num[q], wv * cv);
    atomicAdd(&cnt[q], 1.0f);
  }
}

// ---- K5: cong_node ----
__global__ void k_cong(const float* __restrict__ den, const float* __restrict__ num,
                       const float* __restrict__ cnt, float* __restrict__ cong) {
  int n = blockIdx.x * blockDim.x + threadIdx.x;
  if (n >= NN) return;
  float c = cnt[n];
  cong[n] = (c > 0.f) ? (num[n] / den[n]) / c : 0.f;
}

// ---- K_prep: transpose + bf16-convert W0 [256x256] and W1 [256x128] ----
__global__ void k_prep(const float* __restrict__ W0, const float* __restrict__ W1,
                       ushort* __restrict__ w0t, ushort* __restrict__ w1t) {
  __shared__ float tl[32][33];
  int b = blockIdx.x;
  const float* src; ushort* dst; int N, tk, tn;
  if (b < 64) { src = W0; dst = w0t; N = 256; tk = b >> 3; tn = b & 7; }
  else        { b -= 64; src = W1; dst = w1t; N = 128; tk = b >> 2; tn = b & 3; }
  int tx = threadIdx.x & 31, ty = threadIdx.x >> 5;
#pragma unroll
  for (int yy = 0; yy < 32; yy += 8)
    tl[ty + yy][tx] = src[(size_t)(tk * 32 + ty + yy) * N + tn * 32 + tx];
  __syncthreads();
#pragma unroll
  for (int yy = 0; yy < 32; yy += 8)
    dst[(size_t)(tn * 32 + ty + yy) * 256 + tk * 32 + tx] = f2bf(tl[tx][ty + yy]);
}

// ---- K6: persistent WEIGHT-STATIONARY fused MFMA MLP. W0 slice lives in VGPRs ----
__global__ __launch_bounds__(256, 2) void k_mlp(
    const char* __restrict__ qnodes, const float* __restrict__ nscale,
    const char* __restrict__ qnbrs, const float* __restrict__ nbscale,
    const int* __restrict__ ssrc, const int* __restrict__ sdst,
    const float* __restrict__ cong,
    const ushort* __restrict__ w0t, const ushort* __restrict__ w1t,
    const float* __restrict__ b0, const float* __restrict__ g0, const float* __restrict__ be0,
    const float* __restrict__ b1, const float* __restrict__ g1, const float* __restrict__ be1,
    const float* __restrict__ Wp, const float* __restrict__ bp,
    const float* __restrict__ Ww, const float* __restrict__ bw,
    const float* __restrict__ sscale, const float* __restrict__ sshift,
    const float* __restrict__ craw, float* __restrict__ out) {
  __shared__ ushort tile[32][256];
  __shared__ float pstatA[32][8];
  __shared__ float pstatB[32][8];
  __shared__ float pstatC[32][8];
  __shared__ float nsimb[32];
  __shared__ int   eidx[32][2];

  const int t = threadIdx.x;
  const int w = t >> 6, l = t & 63;
  const int li = l & 15, hi = l >> 4;
  const int r8 = t >> 3, q8 = t & 7;
  const int swl = (li & 7) << 3;
  const int n0 = w * 64;
  const int n2 = w * 32;

  // ---- hoisted uniforms & per-col loop-invariant params ----
  float u0 = softplusf(craw[0]), u1 = softplusf(craw[1]), u2 = softplusf(craw[2]);
  float usum = u0 + u1 + u2;
  float c0 = u0 / usum, c1 = u1 / usum, c2 = u2 / usum;
  float sc = sscale[0], sh = sshift[0];
  float bp0 = bp[0], bw0 = bw[0], ww128 = Ww[128];
  float b0v[4], g0v[4], be0v[4];
#pragma unroll
  for (int nf = 0; nf < 4; nf++) {
    int col = n0 + nf * 16 + li;
    b0v[nf] = b0[col]; g0v[nf] = g0[col]; be0v[nf] = be0[col];
  }
  float b1v[2], g1v[2], be1v[2], wpv[2], wwv[2];
#pragma unroll
  for (int nf = 0; nf < 2; nf++) {
    int col = n2 + nf * 16 + li;
    b1v[nf] = b1[col]; g1v[nf] = g1[col]; be1v[nf] = be1[col];
    wpv[nf] = Wp[col]; wwv[nf] = Ww[col];
  }

  // ---- preload this wave's W0 slice into registers (128 VGPR) ----
  short8 w0r[8][4];
#pragma unroll
  for (int kk = 0; kk < 8; kk++)
#pragma unroll
    for (int nf = 0; nf < 4; nf++)
      w0r[kk][nf] = *(const short8*)(w0t + (size_t)(n0 + nf * 16 + li) * 256 + kk * 32 + hi * 8);

  for (int tl = blockIdx.x; tl < MTILES; tl += MGRID) {
    const int s0 = tl * 32;
    if (t < 32) { eidx[t][0] = ssrc[s0 + t]; eidx[t][1] = sdst[s0 + t]; }

    // ---- gather + stage combined = [a | m] bf16 (16 elems/thread), swizzled ----
    int es = ssrc[s0 + r8], ed = sdst[s0 + r8];
    float sxs = nscale[es], sxd = nscale[ed];
    float nbs = nbscale[es] * nbscale[ed];
    uint4 xu = ((const uint4*)(qnodes + (size_t)es * CC))[q8];
    uint4 yu = ((const uint4*)(qnodes + (size_t)ed * CC))[q8];
    uint4 xn = ((const uint4*)(qnbrs + (size_t)es * CC))[q8];
    uint4 yn = ((const uint4*)(qnbrs + (size_t)ed * CC))[q8];
    {
      unsigned xd[4] = {xu.x, xu.y, xu.z, xu.w};
      unsigned yd[4] = {yu.x, yu.y, yu.z, yu.w};
      int sw = (r8 & 7) << 3;
#pragma unroll
      for (int c = 0; c < 2; c++) {
        float fa[8], fm[8];
#pragma unroll
        for (int dk = 0; dk < 8; dk++) {
          int dd = c * 2 + (dk >> 2), k = dk & 3;
          float fx = (float)(((int)(xd[dd] << (24 - 8 * k))) >> 24) * sxs;
          float fy = (float)(((int)(yd[dd] << (24 - 8 * k))) >> 24) * sxd;
          fa[dk] = fx + fy;
          fm[dk] = fx * fy;
        }
        uint4 ua, um;
        ua.x = cvtpk_bf16(fa[0], fa[1]); ua.y = cvtpk_bf16(fa[2], fa[3]);
        ua.z = cvtpk_bf16(fa[4], fa[5]); ua.w = cvtpk_bf16(fa[6], fa[7]);
        um.x = cvtpk_bf16(fm[0], fm[1]); um.y = cvtpk_bf16(fm[2], fm[3]);
        um.z = cvtpk_bf16(fm[4], fm[5]); um.w = cvtpk_bf16(fm[6], fm[7]);
        int base = q8 * 16 + c * 8;
        *(uint4*)&tile[r8][base ^ sw] = ua;
        *(uint4*)&tile[r8][(128 + base) ^ sw] = um;
      }
    }
    // ---- nbrs similarity ----
    {
      int acc8 = 0;
      acc8 = sdot4i(xn.x, yn.x, acc8); acc8 = sdot4i(xn.y, yn.y, acc8);
      acc8 = sdot4i(xn.z, yn.z, acc8); acc8 = sdot4i(xn.w, yn.w, acc8);
      acc8 += __shfl_xor(acc8, 1, 64);
      acc8 += __shfl_xor(acc8, 2, 64);
      acc8 += __shfl_xor(acc8, 4, 64);
      if (q8 == 0) nsimb[r8] = (float)acc8 * nbs;
    }
    __syncthreads();                        // B1: tile ready

    // ---- GEMM1: h cols [n0, n0+64), weights from REGISTERS ----
    f32x4 acc[4][2];
#pragma unroll
    for (int nf = 0; nf < 4; nf++) {
      float bv = b0v[nf];
      acc[nf][0] = {bv, bv, bv, bv};
      acc[nf][1] = {bv, bv, bv, bv};
    }
#pragma unroll
    for (int kk = 0; kk < 8; kk++) {
      short8 a[2];
      a[0] = *(const short8*)&tile[li][(kk * 32 + hi * 8) ^ swl];
      a[1] = *(const short8*)&tile[16 + li][(kk * 32 + hi * 8) ^ swl];
#pragma unroll
      for (int nf = 0; nf < 4; nf++)
#pragma unroll
        for (int ef = 0; ef < 2; ef++)
          acc[nf][ef] = __builtin_amdgcn_mfma_f32_16x16x32_bf16(a[ef], w0r[kk][nf], acc[nf][ef], 0, 0, 0);
    }

    // ---- LN1 partials -> pstatA ----
    {
      f32x4 ps[2], qs[2];
#pragma unroll
      for (int ef = 0; ef < 2; ef++) {
        ps[ef] = acc[0][ef] + acc[1][ef] + acc[2][ef] + acc[3][ef];
        qs[ef] = acc[0][ef] * acc[0][ef] + acc[1][ef] * acc[1][ef]
               + acc[2][ef] * acc[2][ef] + acc[3][ef] * acc[3][ef];
      }
#pragma unroll
      for (int ef = 0; ef < 2; ef++)
#pragma unroll
        for (int j = 0; j < 4; j++)
#pragma unroll
          for (int off = 1; off < 16; off <<= 1) {
            ps[ef][j] += __shfl_xor(ps[ef][j], off, 64);
            qs[ef][j] += __shfl_xor(qs[ef][j], off, 64);
          }
      if (li < 4) {
#pragma unroll
        for (int ef = 0; ef < 2; ef++) {
          int r = ef * 16 + hi * 4 + li;
          pstatA[r][2 * w] = ps[ef][li];
          pstatA[r][2 * w + 1] = qs[ef][li];
        }
      }
    }
    __syncthreads();                        // B2: pstatA ready

    // ---- LN1 normalize + relu -> tile ----
    {
      float mu1[2][4], rs1[2][4];
#pragma unroll
      for (int ef = 0; ef < 2; ef++)
#pragma unroll
        for (int j = 0; j < 4; j++) {
          int r = ef * 16 + hi * 4 + j;
          float4 pa = *(const float4*)&pstatA[r][0];
          float4 pb = *(const float4*)&pstatA[r][4];
          float s = pa.x + pa.z + pb.x + pb.z;
          float sq = pa.y + pa.w + pb.y + pb.w;
          float mu = s * (1.f / 256.f);
          mu1[ef][j] = mu;
          rs1[ef][j] = rsqrtf(sq * (1.f / 256.f) - mu * mu + 1e-5f);
        }
#pragma unroll
      for (int nf = 0; nf < 4; nf++) {
        int col = n0 + nf * 16 + li;
        float gv = g0v[nf], bev = be0v[nf];
#pragma unroll
        for (int ef = 0; ef < 2; ef++)
#pragma unroll
          for (int j = 0; j < 4; j++) {
            int r = ef * 16 + hi * 4 + j;
            float v = fmaxf((acc[nf][ef][j] - mu1[ef][j]) * rs1[ef][j] * gv + bev, 0.f);
            tile[r][col ^ ((r & 7) << 3)] = f2bf(v);
          }
      }
    }
    __syncthreads();                        // B3: h_ln ready

    // ---- GEMM2: ef cols [n2, n2+32), w1 streamed (L1-resident, 16 KB/wave) ----
    f32x4 acc2[2][2];
#pragma unroll
    for (int nf = 0; nf < 2; nf++) {
      float bv = b1v[nf];
      acc2[nf][0] = {bv, bv, bv, bv};
      acc2[nf][1] = {bv, bv, bv, bv};
    }
#pragma unroll
    for (int kk = 0; kk < 8; kk++) {
      short8 a[2], b[2];
      a[0] = *(const short8*)&tile[li][(kk * 32 + hi * 8) ^ swl];
      a[1] = *(const short8*)&tile[16 + li][(kk * 32 + hi * 8) ^ swl];
#pragma unroll
      for (int nf = 0; nf < 2; nf++)
        b[nf] = *(const short8*)(w1t + (size_t)(n2 + nf * 16 + li) * 256 + kk * 32 + hi * 8);
#pragma unroll
      for (int nf = 0; nf < 2; nf++)
#pragma unroll
        for (int ef = 0; ef < 2; ef++)
          acc2[nf][ef] = __builtin_amdgcn_mfma_f32_16x16x32_bf16(a[ef], b[nf], acc2[nf][ef], 0, 0, 0);
    }

    // ---- LN2 partials -> pstatB ----
    {
      f32x4 ps[2], qs[2];
#pragma unroll
      for (int ef = 0; ef < 2; ef++) {
        ps[ef] = acc2[0][ef] + acc2[1][ef];
        qs[ef] = acc2[0][ef] * acc2[0][ef] + acc2[1][ef] * acc2[1][ef];
      }
#pragma unroll
      for (int ef = 0; ef < 2; ef++)
#pragma unroll
        for (int j = 0; j < 4; j++)
#pragma unroll
          for (int off = 1; off < 16; off <<= 1) {
            ps[ef][j] += __shfl_xor(ps[ef][j], off, 64);
            qs[ef][j] += __shfl_xor(qs[ef][j], off, 64);
          }
      if (li < 4) {
#pragma unroll
        for (int ef = 0; ef < 2; ef++) {
          int r = ef * 16 + hi * 4 + li;
          pstatB[r][2 * w] = ps[ef][li];
          pstatB[r][2 * w + 1] = qs[ef][li];
        }
      }
    }
    __syncthreads();                        // B4: pstatB ready

    // ---- LN2 normalize + relu + head partials -> pstatC ----
    {
      float pdp[2][4] = {{0,0,0,0},{0,0,0,0}};
      float wsp[2][4] = {{0,0,0,0},{0,0,0,0}};
      float mu2[2][4], rs2[2][4];
#pragma unroll
      for (int ef = 0; ef < 2; ef++)
#pragma unroll
        for (int j = 0; j < 4; j++) {
          int r = ef * 16 + hi * 4 + j;
          float4 pa = *(const float4*)&pstatB[r][0];
          float4 pb = *(const float4*)&pstatB[r][4];
          float s = pa.x + pa.z + pb.x + pb.z;
          float sq = pa.y + pa.w + pb.y + pb.w;
          float mu = s * (1.f / 128.f);
          mu2[ef][j] = mu;
          rs2[ef][j] = rsqrtf(sq * (1.f / 128.f) - mu * mu + 1e-5f);
        }
#pragma unroll
      for (int nf = 0; nf < 2; nf++) {
        float gv = g1v[nf], bev = be1v[nf];
        float wp_ = wpv[nf], ww_ = wwv[nf];
#pragma unroll
        for (int ef = 0; ef < 2; ef++)
#pragma unroll
          for (int j = 0; j < 4; j++) {
            float e = fmaxf((acc2[nf][ef][j] - mu2[ef][j]) * rs2[ef][j] * gv + bev, 0.f);
            pdp[ef][j] += e * wp_;
            wsp[ef][j] += e * ww_;
          }
      }
#pragma unroll
      for (int ef = 0; ef < 2; ef++)
#pragma unroll
        for (int j = 0; j < 4; j++)
#pragma unroll
          for (int off = 1; off < 16; off <<= 1) {
            pdp[ef][j] += __shfl_xor(pdp[ef][j], off, 64);
            wsp[ef][j] += __shfl_xor(wsp[ef][j], off, 64);
          }
      if (li < 4) {
#pragma unroll
        for (int ef = 0; ef < 2; ef++) {
          int r = ef * 16 + hi * 4 + li;
          pstatC[r][2 * w] = pdp[ef][li];
          pstatC[r][2 * w + 1] = wsp[ef][li];
        }
      }
    }

    // snapshot per-edge values into regs BEFORE B5 (avoids WAR with next iteration)
    int es_o = 0, ed_o = 0; float ns_o = 0.f;
    if (t < 32) { es_o = eidx[t][0]; ed_o = eidx[t][1]; ns_o = nsimb[t]; }
    __syncthreads();                        // B5: pstatC ready

    if (t < 32) {
      float4 pa = *(const float4*)&pstatC[t][0];
      float4 pb = *(const float4*)&pstatC[t][4];
      float pd = pa.x + pa.z + pb.x + pb.z;
      float ws = pa.y + pa.w + pb.y + pb.w;
      int sidx = s0 + t;
      out[3 * sidx + 0] = c0 * (pd + bp0);
      out[3 * sidx + 1] = c1 * (sc * (ns_o + sh));
      out[3 * sidx + 2] = c2 * (sc * (cong[es_o] + cong[ed_o] + sh));
      out[3 * ESn + sidx] = fmaxf(ws + ns_o * ww128 + bw0, 0.f);
    }
    if (tl == 0 && t == 0) {
      out[4 * ESn + 0] = c0; out[4 * ESn + 1] = c1; out[4 * ESn + 2] = c2;
    }
  }
}

} // namespace

extern "C" void kernel_launch(void* const* d_in, const int* in_sizes, int n_in,
                              void* d_out, int out_size, void* d_ws, size_t ws_size,
                              hipStream_t stream) {
  (void)in_sizes; (void)n_in; (void)out_size; (void)ws_size;
  const float* nodes  = (const float*)d_in[0];
  const float* nbrs   = (const float*)d_in[1];
  const int* sup_src  = (const int*)d_in[2];
  const int* sup_dst  = (const int*)d_in[3];
  const int* msg_src  = (const int*)d_in[4];
  const int* msg_dst  = (const int*)d_in[5];
  // d_in[6] message_edgestr: dead
  const float* W0  = (const float*)d_in[7];
  const float* b0  = (const float*)d_in[8];
  const float* g0  = (const float*)d_in[9];
  const float* be0 = (const float*)d_in[10];
  const float* W1  = (const float*)d_in[11];
  const float* b1  = (const float*)d_in[12];
  const float* g1  = (const float*)d_in[13];
  const float* be1 = (const float*)d_in[14];
  const float* Wp  = (const float*)d_in[15];
  const float* bp  = (const float*)d_in[16];
  const float* Ww  = (const float*)d_in[17];
  const float* bw  = (const float*)d_in[18];
  const float* sscale = (const float*)d_in[19];
  const float* sshift = (const float*)d_in[20];
  const float* craw   = (const float*)d_in[21];
  // d_in[22..27] mm_*: dead
  float* out = (float*)d_out;

  char* p = (char*)d_ws;
  auto take = [&](size_t bytes) -> char* {
    char* r = p; p += (bytes + 255) & ~(size_t)255; return r;
  };
  ushort* w0t     = (ushort*)take((size_t)256 * 256 * 2);
  ushort* w1t     = (ushort*)take((size_t)128 * 256 * 2);
  char*   qnodes  = take((size_t)NN * CC);
  char*   qunit   = take((size_t)NN * CC);
  char*   qnbrs   = take((size_t)NN * CC);
  float*  nscale  = (float*)take((size_t)NN * 4);
  float*  nbscale = (float*)take((size_t)NN * 4);
  int*    pidx    = (int*)take((size_t)NN * 4);
  int*    qnode   = (int*)take((size_t)NN * 4);
  float*  den     = (float*)take((size_t)NN * 4);
  float*  num     = (float*)take((size_t)NN * 4);
  float*  cnt     = (float*)take((size_t)NN * 4);
  float*  cong    = (float*)take((size_t)NN * 4);

  k_init<<<(NN + 255) / 256, 256, 0, stream>>>(pidx, den, num, cnt);
  k_cvtq<<<(2 * NN + 15) / 16, 256, 0, stream>>>(nodes, nbrs, qnodes, qunit, qnbrs,
                                                 nscale, nbscale);
  k_prep<<<96, 256, 0, stream>>>(W0, W1, w0t, w1t);
  k_partner<<<(2 * ESn + 255) / 256, 256, 0, stream>>>(sup_src, sup_dst, pidx);
  k_qnode<<<(NN + 255) / 256, 256, 0, stream>>>(pidx, sup_src, sup_dst, qnode);
  k_cos8<<<EMn / 32, 256, 0, stream>>>(qunit, qnode, msg_src, msg_dst, den, num, cnt);
  k_cong<<<(NN + 255) / 256, 256, 0, stream>>>(den, num, cnt, cong);
  k_mlp<<<MGRID, 256, 0, stream>>>(qnodes, nscale, qnbrs, nbscale,
                                   sup_src, sup_dst, cong,
                                   w0t, w1t, b0, g0, be0, b1, g1, be1,
                                   Wp, bp, Ww, bw, sscale, sshift, craw, out);
}

// Round 9
// 322.833 us; speedup vs baseline: 1.3201x; 1.3201x over previous
//
#include <hip/hip_runtime.h>
#include <math.h>

namespace {

constexpr int NN  = 50000;
constexpr int CC  = 128;
constexpr int EMn = 1000000;
constexpr int ESn = 200000;
constexpr int MLP_TILES   = ESn / 64;     // 3125 tiles of 64 edges
constexpr int COS_WORKERS = 3125;         // odd blocks; 10 chunks of 32 edges each
constexpr int COS_CHUNKS  = EMn / 32;     // 31250

using f32x4  = __attribute__((ext_vector_type(4))) float;
using short8 = __attribute__((ext_vector_type(8))) short;

__device__ __forceinline__ ushort f2bf(float f) {
  unsigned u = __float_as_uint(f);
  return (ushort)((u + 0x7fffu + ((u >> 16) & 1u)) >> 16);   // RNE
}
__device__ __forceinline__ float softplusf(float x) {
  return (x > 20.f) ? x : log1pf(expf(x));
}
__device__ __forceinline__ int sdot4i(unsigned a, unsigned b, int c) {
#if __has_builtin(__builtin_amdgcn_sdot4)
  return __builtin_amdgcn_sdot4((int)a, (int)b, c, false);
#else
  int r = c;
#pragma unroll
  for (int k = 0; k < 4; k++) {
    int xa = ((int)(a << (24 - 8 * k))) >> 24;
    int xb = ((int)(b << (24 - 8 * k))) >> 24;
    r += xa * xb;
  }
  return r;
#endif
}
__device__ __forceinline__ unsigned pack4(float a, float b, float c, float d) {
  int ia = __float2int_rn(a), ib = __float2int_rn(b);
  int ic = __float2int_rn(c), id = __float2int_rn(d);
  return (unsigned)(ia & 255) | ((unsigned)(ib & 255) << 8) |
         ((unsigned)(ic & 255) << 16) | ((unsigned)(id & 255) << 24);
}

// ---- K0: init scratch ----
__global__ void k_init(int* __restrict__ pidx, float* __restrict__ den,
                       float* __restrict__ num, float* __restrict__ cnt) {
  int i = blockIdx.x * blockDim.x + threadIdx.x;
  if (i < NN) { pidx[i] = -1; den[i] = 0.f; num[i] = 0.f; cnt[i] = 0.f; }
}

// ---- K_cvtq: per-row int8 quantization ----
__global__ void k_cvtq(const float* __restrict__ nodes, const float* __restrict__ nbrs,
                       char* __restrict__ qnodes, char* __restrict__ qunit,
                       char* __restrict__ qnbrs, float* __restrict__ nscale,
                       float* __restrict__ nbscale) {
  int row = blockIdx.x * 16 + (threadIdx.x >> 4);
  int li = threadIdx.x & 15;
  if (row >= 2 * NN) return;
  bool isn = row < NN;
  int r = isn ? row : row - NN;
  const float* src = (isn ? nodes : nbrs) + (size_t)r * CC;
  float4 x0 = *(const float4*)(src + li * 8);
  float4 x1 = *(const float4*)(src + li * 8 + 4);
  float v[8] = {x0.x, x0.y, x0.z, x0.w, x1.x, x1.y, x1.z, x1.w};
  float amax = 0.f, sq = 0.f;
#pragma unroll
  for (int j = 0; j < 8; j++) { amax = fmaxf(amax, fabsf(v[j])); sq += v[j] * v[j]; }
#pragma unroll
  for (int off = 1; off < 16; off <<= 1) {
    amax = fmaxf(amax, __shfl_xor(amax, off, 64));
    sq += __shfl_xor(sq, off, 64);
  }
  amax = fmaxf(amax, 1e-8f);
  float rs = 127.f / amax;
  uint2 p;
  p.x = pack4(v[0] * rs, v[1] * rs, v[2] * rs, v[3] * rs);
  p.y = pack4(v[4] * rs, v[5] * rs, v[6] * rs, v[7] * rs);
  if (isn) {
    *(uint2*)(qnodes + (size_t)r * CC + li * 8) = p;
    float ru = 127.f / fmaxf(sqrtf(sq), 1e-8f);
    uint2 pu;
    pu.x = pack4(v[0] * ru, v[1] * ru, v[2] * ru, v[3] * ru);
    pu.y = pack4(v[4] * ru, v[5] * ru, v[6] * ru, v[7] * ru);
    *(uint2*)(qunit + (size_t)r * CC + li * 8) = pu;
    if (li == 0) nscale[r] = amax / 127.f;
  } else {
    *(uint2*)(qnbrs + (size_t)r * CC + li * 8) = p;
    if (li == 0) nbscale[r] = amax / 127.f;
  }
}

// ---- K2: partner_index scatter-max ----
__global__ void k_partner(const int* __restrict__ ss, const int* __restrict__ sd,
                          int* __restrict__ pidx) {
  int i = blockIdx.x * blockDim.x + threadIdx.x;
  if (i >= 2 * ESn) return;
  int partner = (i < ESn) ? sd[i] : ss[i - ESn];
  atomicMax(&pidx[partner], i);
}

// ---- K_qnode: per-node query lookup ----
__global__ void k_qnode(const int* __restrict__ pidx, const int* __restrict__ ss,
                        const int* __restrict__ sd, int* __restrict__ qnode) {
  int n = blockIdx.x * blockDim.x + threadIdx.x;
  if (n >= NN) return;
  int pi = pidx[n];
  qnode[n] = (pi < 0) ? -1 : ((pi < ESn) ? ss[pi] : sd[pi - ESn]);
}

// ---- K5: cong_node ----
__global__ void k_cong(const float* __restrict__ den, const float* __restrict__ num,
                       const float* __restrict__ cnt, float* __restrict__ cong) {
  int n = blockIdx.x * blockDim.x + threadIdx.x;
  if (n >= NN) return;
  float c = cnt[n];
  cong[n] = (c > 0.f) ? (num[n] / den[n]) / c : 0.f;
}

// ---- K_prep: transpose + bf16-convert W0 [256x256] and W1 [256x128] ----
__global__ void k_prep(const float* __restrict__ W0, const float* __restrict__ W1,
                       ushort* __restrict__ w0t, ushort* __restrict__ w1t) {
  __shared__ float tl[32][33];
  int b = blockIdx.x;
  const float* src; ushort* dst; int N, tk, tn;
  if (b < 64) { src = W0; dst = w0t; N = 256; tk = b >> 3; tn = b & 7; }
  else        { b -= 64; src = W1; dst = w1t; N = 128; tk = b >> 2; tn = b & 3; }
  int tx = threadIdx.x & 31, ty = threadIdx.x >> 5;
#pragma unroll
  for (int yy = 0; yy < 32; yy += 8)
    tl[ty + yy][tx] = src[(size_t)(tk * 32 + ty + yy) * N + tn * 32 + tx];
  __syncthreads();
#pragma unroll
  for (int yy = 0; yy < 32; yy += 8)
    dst[(size_t)(tn * 32 + ty + yy) * 256 + tk * 32 + tx] = f2bf(tl[tx][ty + yy]);
}

// ---- K_finish: P_cong column + coeff outputs ----
__global__ void k_finish(const int* __restrict__ ssrc, const int* __restrict__ sdst,
                         const float* __restrict__ cong, const float* __restrict__ sscale,
                         const float* __restrict__ sshift, const float* __restrict__ craw,
                         float* __restrict__ out) {
  int i = blockIdx.x * blockDim.x + threadIdx.x;
  float u0 = softplusf(craw[0]), u1 = softplusf(craw[1]), u2 = softplusf(craw[2]);
  float usum = u0 + u1 + u2;
  float c2 = u2 / usum;
  if (i < ESn)
    out[3 * i + 2] = c2 * (sscale[0] * (cong[ssrc[i]] + cong[sdst[i]] + sshift[0]));
  if (i == 0) {
    out[4 * ESn + 0] = u0 / usum;
    out[4 * ESn + 1] = u1 / usum;
    out[4 * ESn + 2] = c2;
  }
}

// ---- K_fused: even blocks run an MLP tile (64 edges); odd blocks run cos chunks ----
__global__ __launch_bounds__(256) void k_fused(
    const char* __restrict__ qnodes, const float* __restrict__ nscale,
    const char* __restrict__ qnbrs, const float* __restrict__ nbscale,
    const char* __restrict__ qunit, const int* __restrict__ qnode,
    const int* __restrict__ ssrc, const int* __restrict__ sdst,
    const int* __restrict__ ms, const int* __restrict__ md,
    float* __restrict__ den, float* __restrict__ num, float* __restrict__ cnt,
    const ushort* __restrict__ w0t, const ushort* __restrict__ w1t,
    const float* __restrict__ b0, const float* __restrict__ g0, const float* __restrict__ be0,
    const float* __restrict__ b1, const float* __restrict__ g1, const float* __restrict__ be1,
    const float* __restrict__ Wp, const float* __restrict__ bp,
    const float* __restrict__ Ww, const float* __restrict__ bw,
    const float* __restrict__ sscale, const float* __restrict__ sshift,
    const float* __restrict__ craw, float* __restrict__ out) {
  __shared__ ushort tile[64][256];
  __shared__ float pstat[4][64][2];
  __shared__ float mustd[64][2];
  __shared__ float nsimb[64];
  __shared__ int   eidx[64][2];

  const int t = threadIdx.x;

  // ================= COS PATH (odd blocks) =================
  if (blockIdx.x & 1) {
    int worker = blockIdx.x >> 1;
    int slot = t >> 3, li = t & 7;
    for (int chunk = worker; chunk < COS_CHUNKS; chunk += COS_WORKERS) {
      int e = chunk * 32 + slot;
      int q = qnode[md[e]];
      if (q >= 0) {                          // uniform per 8-lane group
        int s = ms[e];
        uint4 a = ((const uint4*)(qunit + (size_t)q * CC))[li];
        uint4 b = ((const uint4*)(qunit + (size_t)s * CC))[li];
        int acc = 0;
        acc = sdot4i(a.x, b.x, acc); acc = sdot4i(a.y, b.y, acc);
        acc = sdot4i(a.z, b.z, acc); acc = sdot4i(a.w, b.w, acc);
#pragma unroll
        for (int off = 1; off < 8; off <<= 1) acc += __shfl_xor(acc, off, 64);
        if (li == 0) {
          float cv = (float)acc * (1.0f / (127.f * 127.f));
          float wv = expf(10.0f * cv);       // softmax shift-invariant: no max pass
          atomicAdd(&den[q], wv);
          atomicAdd(&num[q], wv * cv);
          atomicAdd(&cnt[q], 1.0f);
        }
      }
    }
    return;
  }

  // ================= MLP PATH (even blocks) =================
  const int w = t >> 6, l = t & 63;
  const int li = l & 15, hi = l >> 4;
  const int s0 = (blockIdx.x >> 1) * 64;

  if (t < 64) { eidx[t][0] = ssrc[s0 + t]; eidx[t][1] = sdst[s0 + t]; }

  // ---- stage combined = [a | m] bf16 from int8 rows; 4 lanes/row ----
  {
    int r = w * 16 + (l >> 2), q4 = l & 3;
    int es = ssrc[s0 + r], ed = sdst[s0 + r];
    float sxs = nscale[es], sxd = nscale[ed];
    const uint4* xs = (const uint4*)(qnodes + (size_t)es * CC) + q4 * 2;
    const uint4* ys = (const uint4*)(qnodes + (size_t)ed * CC) + q4 * 2;
    int sw = (r & 7) << 3;
#pragma unroll
    for (int i = 0; i < 2; i++) {
      uint4 xu = xs[i], yu = ys[i];
      unsigned xd[4] = {xu.x, xu.y, xu.z, xu.w};
      unsigned yd[4] = {yu.x, yu.y, yu.z, yu.w};
#pragma unroll
      for (int c = 0; c < 2; c++) {
        short8 a8, m8;
#pragma unroll
        for (int dk = 0; dk < 8; dk++) {
          int dd = c * 2 + (dk >> 2), k = dk & 3;
          float fx = (float)(((int)(xd[dd] << (24 - 8 * k))) >> 24) * sxs;
          float fy = (float)(((int)(yd[dd] << (24 - 8 * k))) >> 24) * sxd;
          a8[dk] = (short)f2bf(fx + fy);
          m8[dk] = (short)f2bf(fx * fy);
        }
        int base = q4 * 32 + i * 16 + c * 8;
        *(short8*)&tile[r][base ^ sw] = a8;
        *(short8*)&tile[r][(128 + base) ^ sw] = m8;
      }
    }
  }
  __syncthreads();                          // B1

  const int swl = (li & 7) << 3;
  const int n0 = w * 64;

  // ---- GEMM1: h cols [n0, n0+64) for all 64 edges ----
  f32x4 acc[4][4];                          // [nf][ef]
#pragma unroll
  for (int nf = 0; nf < 4; nf++) {
    float bv = b0[n0 + nf * 16 + li];
#pragma unroll
    for (int ef = 0; ef < 4; ef++) acc[nf][ef] = {bv, bv, bv, bv};
  }
#pragma unroll
  for (int kk = 0; kk < 8; kk++) {
    short8 a[4], b[4];
#pragma unroll
    for (int ef = 0; ef < 4; ef++)
      a[ef] = *(const short8*)&tile[ef * 16 + li][(kk * 32 + hi * 8) ^ swl];
#pragma unroll
    for (int nf = 0; nf < 4; nf++)
      b[nf] = *(const short8*)(w0t + (size_t)(n0 + nf * 16 + li) * 256 + kk * 32 + hi * 8);
#pragma unroll
    for (int nf = 0; nf < 4; nf++)
#pragma unroll
      for (int ef = 0; ef < 4; ef++)
        acc[nf][ef] = __builtin_amdgcn_mfma_f32_16x16x32_bf16(a[ef], b[nf], acc[nf][ef], 0, 0, 0);
  }

  // ---- LN1 partials ----
  {
    f32x4 ps[4], qs[4];
#pragma unroll
    for (int ef = 0; ef < 4; ef++) {
      ps[ef] = acc[0][ef] + acc[1][ef] + acc[2][ef] + acc[3][ef];
      qs[ef] = acc[0][ef] * acc[0][ef] + acc[1][ef] * acc[1][ef]
             + acc[2][ef] * acc[2][ef] + acc[3][ef] * acc[3][ef];
    }
#pragma unroll
    for (int ef = 0; ef < 4; ef++)
#pragma unroll
      for (int j = 0; j < 4; j++)
#pragma unroll
        for (int off = 1; off < 16; off <<= 1) {
          ps[ef][j] += __shfl_xor(ps[ef][j], off, 64);
          qs[ef][j] += __shfl_xor(qs[ef][j], off, 64);
        }
    if (li < 4) {
#pragma unroll
      for (int ef = 0; ef < 4; ef++) {
        int r = ef * 16 + hi * 4 + li;
        pstat[w][r][0] = ps[ef][li];
        pstat[w][r][1] = qs[ef][li];
      }
    }
  }
  __syncthreads();                          // B2
  if (t < 64) {
    float s = 0.f, sq = 0.f;
#pragma unroll
    for (int ww = 0; ww < 4; ww++) { s += pstat[ww][t][0]; sq += pstat[ww][t][1]; }
    float mu = s * (1.f / 256.f);
    float var = sq * (1.f / 256.f) - mu * mu;
    mustd[t][0] = mu; mustd[t][1] = rsqrtf(var + 1e-5f);
  }

  // ---- nbrs similarity (int8 dot; wave w -> edges [16w,16w+16), 4 lanes/edge) ----
  {
    int e = w * 16 + (l >> 2), q4 = l & 3;
    int es = eidx[e][0], ed = eidx[e][1];
    const uint4* xs = (const uint4*)(qnbrs + (size_t)es * CC) + q4 * 2;
    const uint4* ys = (const uint4*)(qnbrs + (size_t)ed * CC) + q4 * 2;
    int acc8 = 0;
#pragma unroll
    for (int i = 0; i < 2; i++) {
      uint4 x = xs[i], y = ys[i];
      acc8 = sdot4i(x.x, y.x, acc8); acc8 = sdot4i(x.y, y.y, acc8);
      acc8 = sdot4i(x.z, y.z, acc8); acc8 = sdot4i(x.w, y.w, acc8);
    }
    acc8 += __shfl_xor(acc8, 1, 64);
    acc8 += __shfl_xor(acc8, 2, 64);
    if (q4 == 0) nsimb[e] = (float)acc8 * nbscale[es] * nbscale[ed];
  }
  __syncthreads();                          // B3

  // ---- LN1 normalize + relu -> tile (h_ln) ----
  {
    float mu[4][4], rs[4][4];
#pragma unroll
    for (int ef = 0; ef < 4; ef++)
#pragma unroll
      for (int j = 0; j < 4; j++) {
        int r = ef * 16 + hi * 4 + j;
        mu[ef][j] = mustd[r][0]; rs[ef][j] = mustd[r][1];
      }
#pragma unroll
    for (int nf = 0; nf < 4; nf++) {
      int col = n0 + nf * 16 + li;
      float gv = g0[col], bev = be0[col];
#pragma unroll
      for (int ef = 0; ef < 4; ef++)
#pragma unroll
        for (int j = 0; j < 4; j++) {
          int r = ef * 16 + hi * 4 + j;
          float v = fmaxf((acc[nf][ef][j] - mu[ef][j]) * rs[ef][j] * gv + bev, 0.f);
          tile[r][col ^ ((r & 7) << 3)] = f2bf(v);
        }
    }
  }
  __syncthreads();                          // B4

  // ---- GEMM2: ef cols [32w, 32w+32) for all 64 edges ----
  const int n2 = w * 32;
  f32x4 acc2[2][4];
#pragma unroll
  for (int nf = 0; nf < 2; nf++) {
    float bv = b1[n2 + nf * 16 + li];
#pragma unroll
    for (int ef = 0; ef < 4; ef++) acc2[nf][ef] = {bv, bv, bv, bv};
  }
#pragma unroll
  for (int kk = 0; kk < 8; kk++) {
    short8 a[4], b[2];
#pragma unroll
    for (int ef = 0; ef < 4; ef++)
      a[ef] = *(const short8*)&tile[ef * 16 + li][(kk * 32 + hi * 8) ^ swl];
#pragma unroll
    for (int nf = 0; nf < 2; nf++)
      b[nf] = *(const short8*)(w1t + (size_t)(n2 + nf * 16 + li) * 256 + kk * 32 + hi * 8);
#pragma unroll
    for (int nf = 0; nf < 2; nf++)
#pragma unroll
      for (int ef = 0; ef < 4; ef++)
        acc2[nf][ef] = __builtin_amdgcn_mfma_f32_16x16x32_bf16(a[ef], b[nf], acc2[nf][ef], 0, 0, 0);
  }

  // ---- LN2 partials ----
  {
    f32x4 ps[4], qs[4];
#pragma unroll
    for (int ef = 0; ef < 4; ef++) {
      ps[ef] = acc2[0][ef] + acc2[1][ef];
      qs[ef] = acc2[0][ef] * acc2[0][ef] + acc2[1][ef] * acc2[1][ef];
    }
#pragma unroll
    for (int ef = 0; ef < 4; ef++)
#pragma unroll
      for (int j = 0; j < 4; j++)
#pragma unroll
        for (int off = 1; off < 16; off <<= 1) {
          ps[ef][j] += __shfl_xor(ps[ef][j], off, 64);
          qs[ef][j] += __shfl_xor(qs[ef][j], off, 64);
        }
    if (li < 4) {
#pragma unroll
      for (int ef = 0; ef < 4; ef++) {
        int r = ef * 16 + hi * 4 + li;
        pstat[w][r][0] = ps[ef][li];
        pstat[w][r][1] = qs[ef][li];
      }
    }
  }
  __syncthreads();                          // B5
  if (t < 64) {
    float s = 0.f, sq = 0.f;
#pragma unroll
    for (int ww = 0; ww < 4; ww++) { s += pstat[ww][t][0]; sq += pstat[ww][t][1]; }
    float mu = s * (1.f / 128.f);
    float var = sq * (1.f / 128.f) - mu * mu;
    mustd[t][0] = mu; mustd[t][1] = rsqrtf(var + 1e-5f);
  }
  __syncthreads();                          // B6

  // ---- LN2 normalize + relu + head partial dots ----
  {
    float mu[4][4], rs[4][4];
#pragma unroll
    for (int ef = 0; ef < 4; ef++)
#pragma unroll
      for (int j = 0; j < 4; j++) {
        int r = ef * 16 + hi * 4 + j;
        mu[ef][j] = mustd[r][0]; rs[ef][j] = mustd[r][1];
      }
    f32x4 pdp[4] = {{0,0,0,0},{0,0,0,0},{0,0,0,0},{0,0,0,0}};
    f32x4 wsp[4] = {{0,0,0,0},{0,0,0,0},{0,0,0,0},{0,0,0,0}};
#pragma unroll
    for (int nf = 0; nf < 2; nf++) {
      int col = n2 + nf * 16 + li;
      float gv = g1[col], bev = be1[col];
      float wpv = Wp[col], wwv = Ww[col];
#pragma unroll
      for (int ef = 0; ef < 4; ef++)
#pragma unroll
        for (int j = 0; j < 4; j++) {
          float e = fmaxf((acc2[nf][ef][j] - mu[ef][j]) * rs[ef][j] * gv + bev, 0.f);
          pdp[ef][j] += e * wpv;
          wsp[ef][j] += e * wwv;
        }
    }
#pragma unroll
    for (int ef = 0; ef < 4; ef++)
#pragma unroll
      for (int j = 0; j < 4; j++)
#pragma unroll
        for (int off = 1; off < 16; off <<= 1) {
          pdp[ef][j] += __shfl_xor(pdp[ef][j], off, 64);
          wsp[ef][j] += __shfl_xor(wsp[ef][j], off, 64);
        }
    if (li < 4) {
#pragma unroll
      for (int ef = 0; ef < 4; ef++) {
        int r = ef * 16 + hi * 4 + li;
        pstat[w][r][0] = pdp[ef][li];
        pstat[w][r][1] = wsp[ef][li];
      }
    }
  }
  __syncthreads();                          // B7

  if (t < 64) {
    float pd = 0.f, ws = 0.f;
#pragma unroll
    for (int ww = 0; ww < 4; ww++) { pd += pstat[ww][t][0]; ws += pstat[ww][t][1]; }
    float nsim = nsimb[t];
    float u0 = softplusf(craw[0]), u1 = softplusf(craw[1]), u2 = softplusf(craw[2]);
    float usum = u0 + u1 + u2;
    float c0 = u0 / usum, c1 = u1 / usum;
    float sc = sscale[0], sh = sshift[0];
    int sidx = s0 + t;
    out[3 * sidx + 0] = c0 * (pd + bp[0]);
    out[3 * sidx + 1] = c1 * (sc * (nsim + sh));
    out[3 * ESn + sidx] = fmaxf(ws + nsim * Ww[128] + bw[0], 0.f);
  }
}

} // namespace

extern "C" void kernel_launch(void* const* d_in, const int* in_sizes, int n_in,
                              void* d_out, int out_size, void* d_ws, size_t ws_size,
                              hipStream_t stream) {
  (void)in_sizes; (void)n_in; (void)out_size; (void)ws_size;
  const float* nodes  = (const float*)d_in[0];
  const float* nbrs   = (const float*)d_in[1];
  const int* sup_src  = (const int*)d_in[2];
  const int* sup_dst  = (const int*)d_in[3];
  const int* msg_src  = (const int*)d_in[4];
  const int* msg_dst  = (const int*)d_in[5];
  // d_in[6] message_edgestr: dead
  const float* W0  = (const float*)d_in[7];
  const float* b0  = (const float*)d_in[8];
  const float* g0  = (const float*)d_in[9];
  const float* be0 = (const float*)d_in[10];
  const float* W1  = (const float*)d_in[11];
  const float* b1  = (const float*)d_in[12];
  const float* g1  = (const float*)d_in[13];
  const float* be1 = (const float*)d_in[14];
  const float* Wp  = (const float*)d_in[15];
  const float* bp  = (const float*)d_in[16];
  const float* Ww  = (const float*)d_in[17];
  const float* bw  = (const float*)d_in[18];
  const float* sscale = (const float*)d_in[19];
  const float* sshift = (const float*)d_in[20];
  const float* craw   = (const float*)d_in[21];
  // d_in[22..27] mm_*: dead
  float* out = (float*)d_out;

  char* p = (char*)d_ws;
  auto take = [&](size_t bytes) -> char* {
    char* r = p; p += (bytes + 255) & ~(size_t)255; return r;
  };
  ushort* w0t     = (ushort*)take((size_t)256 * 256 * 2);
  ushort* w1t     = (ushort*)take((size_t)128 * 256 * 2);
  char*   qnodes  = take((size_t)NN * CC);
  char*   qunit   = take((size_t)NN * CC);
  char*   qnbrs   = take((size_t)NN * CC);
  float*  nscale  = (float*)take((size_t)NN * 4);
  float*  nbscale = (float*)take((size_t)NN * 4);
  int*    pidx    = (int*)take((size_t)NN * 4);
  int*    qnode   = (int*)take((size_t)NN * 4);
  float*  den     = (float*)take((size_t)NN * 4);
  float*  num     = (float*)take((size_t)NN * 4);
  float*  cnt     = (float*)take((size_t)NN * 4);
  float*  cong    = (float*)take((size_t)NN * 4);

  k_init<<<(NN + 255) / 256, 256, 0, stream>>>(pidx, den, num, cnt);
  k_cvtq<<<(2 * NN + 15) / 16, 256, 0, stream>>>(nodes, nbrs, qnodes, qunit, qnbrs,
                                                 nscale, nbscale);
  k_prep<<<96, 256, 0, stream>>>(W0, W1, w0t, w1t);
  k_partner<<<(2 * ESn + 255) / 256, 256, 0, stream>>>(sup_src, sup_dst, pidx);
  k_qnode<<<(NN + 255) / 256, 256, 0, stream>>>(pidx, sup_src, sup_dst, qnode);
  k_fused<<<2 * MLP_TILES, 256, 0, stream>>>(qnodes, nscale, qnbrs, nbscale,
                                             qunit, qnode, sup_src, sup_dst,
                                             msg_src, msg_dst, den, num, cnt,
                                             w0t, w1t, b0, g0, be0, b1, g1, be1,
                                             Wp, bp, Ww, bw, sscale, sshift, craw, out);
  k_cong<<<(NN + 255) / 256, 256, 0, stream>>>(den, num, cnt, cong);
  k_finish<<<(ESn + 255) / 256, 256, 0, stream>>>(sup_src, sup_dst, cong,
                                                  sscale, sshift, craw, out);
}

// Round 10
// 244.562 us; speedup vs baseline: 1.7426x; 1.3200x over previous
//
#include <hip/hip_runtime.h>
#include <math.h>

namespace {

constexpr int NN  = 50000;
constexpr int CC  = 128;
constexpr int EMn = 1000000;
constexpr int ESn = 200000;
constexpr int MLPB = 256;            // persistent blocks (1 per CU)
constexpr int WPB  = 12;             // waves per block
constexpr int NTILES = ESn / 16;     // 12500 tiles of 16 edges
constexpr int NWAVES = MLPB * WPB;   // 3072

using i32x4 = __attribute__((ext_vector_type(4))) int;

__device__ __forceinline__ float softplusf(float x) {
  return (x > 20.f) ? x : log1pf(expf(x));
}
__device__ __forceinline__ int sdot4i(unsigned a, unsigned b, int c) {
#if __has_builtin(__builtin_amdgcn_sdot4)
  return __builtin_amdgcn_sdot4((int)a, (int)b, c, false);
#else
  int r = c;
#pragma unroll
  for (int k = 0; k < 4; k++) {
    int xa = ((int)(a << (24 - 8 * k))) >> 24;
    int xb = ((int)(b << (24 - 8 * k))) >> 24;
    r += xa * xb;
  }
  return r;
#endif
}
__device__ __forceinline__ unsigned pack4(float a, float b, float c, float d) {
  int ia = __float2int_rn(a), ib = __float2int_rn(b);
  int ic = __float2int_rn(c), id = __float2int_rn(d);
  return (unsigned)(ia & 255) | ((unsigned)(ib & 255) << 8) |
         ((unsigned)(ic & 255) << 16) | ((unsigned)(id & 255) << 24);
}

// ---- K0: init scratch ----
__global__ void k_init(int* __restrict__ pidx, double* __restrict__ dencnt,
                       float* __restrict__ num) {
  int i = blockIdx.x * blockDim.x + threadIdx.x;
  if (i < NN) { pidx[i] = -1; dencnt[i] = 0.0; num[i] = 0.f; }
}

// ---- K_cvtq: per-row int8 quantization of nodes/nbrs ----
__global__ void k_cvtq(const float* __restrict__ nodes, const float* __restrict__ nbrs,
                       char* __restrict__ qnodes, char* __restrict__ qunit,
                       char* __restrict__ qnbrs, float* __restrict__ nscale,
                       float* __restrict__ nbscale) {
  int row = blockIdx.x * 16 + (threadIdx.x >> 4);
  int li = threadIdx.x & 15;
  if (row >= 2 * NN) return;
  bool isn = row < NN;
  int r = isn ? row : row - NN;
  const float* src = (isn ? nodes : nbrs) + (size_t)r * CC;
  float4 x0 = *(const float4*)(src + li * 8);
  float4 x1 = *(const float4*)(src + li * 8 + 4);
  float v[8] = {x0.x, x0.y, x0.z, x0.w, x1.x, x1.y, x1.z, x1.w};
  float amax = 0.f, sq = 0.f;
#pragma unroll
  for (int j = 0; j < 8; j++) { amax = fmaxf(amax, fabsf(v[j])); sq += v[j] * v[j]; }
#pragma unroll
  for (int off = 1; off < 16; off <<= 1) {
    amax = fmaxf(amax, __shfl_xor(amax, off, 64));
    sq += __shfl_xor(sq, off, 64);
  }
  amax = fmaxf(amax, 1e-8f);
  float rs = 127.f / amax;
  uint2 p;
  p.x = pack4(v[0] * rs, v[1] * rs, v[2] * rs, v[3] * rs);
  p.y = pack4(v[4] * rs, v[5] * rs, v[6] * rs, v[7] * rs);
  if (isn) {
    *(uint2*)(qnodes + (size_t)r * CC + li * 8) = p;
    float ru = 127.f / fmaxf(sqrtf(sq), 1e-8f);
    uint2 pu;
    pu.x = pack4(v[0] * ru, v[1] * ru, v[2] * ru, v[3] * ru);
    pu.y = pack4(v[4] * ru, v[5] * ru, v[6] * ru, v[7] * ru);
    *(uint2*)(qunit + (size_t)r * CC + li * 8) = pu;
    if (li == 0) nscale[r] = amax / 127.f;
  } else {
    *(uint2*)(qnbrs + (size_t)r * CC + li * 8) = p;
    if (li == 0) nbscale[r] = amax / 127.f;
  }
}

// ---- K2: partner_index scatter-max ----
__global__ void k_partner(const int* __restrict__ ss, const int* __restrict__ sd,
                          int* __restrict__ pidx) {
  int i = blockIdx.x * blockDim.x + threadIdx.x;
  if (i >= 2 * ESn) return;
  int partner = (i < ESn) ? sd[i] : ss[i - ESn];
  atomicMax(&pidx[partner], i);
}

// ---- K_qnode ----
__global__ void k_qnode(const int* __restrict__ pidx, const int* __restrict__ ss,
                        const int* __restrict__ sd, int* __restrict__ qnode) {
  int n = blockIdx.x * blockDim.x + threadIdx.x;
  if (n >= NN) return;
  int pi = pidx[n];
  qnode[n] = (pi < 0) ? -1 : ((pi < ESn) ? ss[pi] : sd[pi - ESn]);
}

// ---- K_prep2: int8 per-col quant of W0/W1 into swizzled [col][k] layout ----
__global__ __launch_bounds__(256) void k_prep2(const float* __restrict__ W0,
                                               const float* __restrict__ W1,
                                               char* __restrict__ w0q, char* __restrict__ w1q,
                                               float* __restrict__ cs0, float* __restrict__ cs1) {
  __shared__ float wmax[4];
  int c = blockIdx.x;
  int k = threadIdx.x;
  bool is0 = c < 256;
  int col = is0 ? c : c - 256;
  float v = is0 ? W0[(size_t)k * 256 + col] : W1[(size_t)k * 128 + col];
  float am = fabsf(v);
#pragma unroll
  for (int off = 1; off < 64; off <<= 1) am = fmaxf(am, __shfl_xor(am, off, 64));
  if ((k & 63) == 0) wmax[k >> 6] = am;
  __syncthreads();
  float amax = fmaxf(fmaxf(wmax[0], wmax[1]), fmaxf(wmax[2], wmax[3]));
  amax = fmaxf(amax, 1e-12f);
  int q = __float2int_rn(v * (127.f / amax));
  char* dst = is0 ? w0q : w1q;
  dst[(size_t)col * 256 + ((((k >> 4) ^ (col & 15))) << 4) + (k & 15)] = (char)q;
  if (k == 0) (is0 ? cs0 : cs1)[col] = amax / 127.f;
}

// ---- K5: cong_node (decode packed den+cnt) ----
__global__ void k_cong(const double* __restrict__ dencnt, const float* __restrict__ num,
                       float* __restrict__ cong) {
  int n = blockIdx.x * blockDim.x + threadIdx.x;
  if (n >= NN) return;
  double dc = dencnt[n];
  double cnt = floor(dc * (1.0 / 4294967296.0) + 0.5);
  double den = dc - cnt * 4294967296.0;
  cong[n] = (cnt > 0.0) ? (float)(((double)num[n] / fmax(den, 1e-30)) / cnt) : 0.f;
}

// ---- K_finish: P_cong column + coeff ----
__global__ void k_finish(const int* __restrict__ ssrc, const int* __restrict__ sdst,
                         const float* __restrict__ cong, const float* __restrict__ sscale,
                         const float* __restrict__ sshift, const float* __restrict__ craw,
                         float* __restrict__ out) {
  int i = blockIdx.x * blockDim.x + threadIdx.x;
  float u0 = softplusf(craw[0]), u1 = softplusf(craw[1]), u2 = softplusf(craw[2]);
  float usum = u0 + u1 + u2;
  float c2 = u2 / usum;
  if (i < ESn)
    out[3 * i + 2] = c2 * (sscale[0] * (cong[ssrc[i]] + cong[sdst[i]] + sshift[0]));
  if (i == 0) {
    out[4 * ESn + 0] = u0 / usum;
    out[4 * ESn + 1] = u1 / usum;
    out[4 * ESn + 2] = c2;
  }
}

// ---- K_big: zero-barrier wave-autonomous MLP (i8 MFMA, LDS weights) + cos phase ----
__global__ __launch_bounds__(768, 3) void k_big(
    const char* __restrict__ qnodes, const float* __restrict__ nscale,
    const char* __restrict__ qnbrs, const float* __restrict__ nbscale,
    const char* __restrict__ qunit, const int* __restrict__ qnode,
    const int* __restrict__ ssrc, const int* __restrict__ sdst,
    const int* __restrict__ ms, const int* __restrict__ md,
    double* __restrict__ dencnt, float* __restrict__ num,
    const char* __restrict__ w0q, const char* __restrict__ w1q,
    const float* __restrict__ cs0g, const float* __restrict__ cs1g,
    const float* __restrict__ b0, const float* __restrict__ g0, const float* __restrict__ be0,
    const float* __restrict__ b1, const float* __restrict__ g1, const float* __restrict__ be1,
    const float* __restrict__ Wp, const float* __restrict__ bp,
    const float* __restrict__ Ww, const float* __restrict__ bw,
    const float* __restrict__ sscale, const float* __restrict__ sshift,
    const float* __restrict__ craw, float* __restrict__ out) {
  __shared__ char  w0s[65536];       // W0 int8 [256 col][256 k], granule-XOR swizzled
  __shared__ char  w1s[32768];       // W1 int8 [128 col][256 k]
  __shared__ float prm[1792];        // cs0,b0,g0,be0 (256ea) | cs1,b1,g1,be1,Wp,Ww (128ea)
  __shared__ char  hln[WPB][4096];   // per-wave h_ln int8 [16 r][256 c] swizzled

  const int t = threadIdx.x;
  for (int i = t; i < 4096; i += 768) ((uint4*)w0s)[i] = ((const uint4*)w0q)[i];
  for (int i = t; i < 2048; i += 768) ((uint4*)w1s)[i] = ((const uint4*)w1q)[i];
  if (t < 256) { prm[t] = cs0g[t]; prm[256 + t] = b0[t]; prm[512 + t] = g0[t]; prm[768 + t] = be0[t]; }
  if (t < 128) { prm[1024 + t] = cs1g[t]; prm[1152 + t] = b1[t]; prm[1280 + t] = g1[t];
                 prm[1408 + t] = be1[t];  prm[1536 + t] = Wp[t]; prm[1664 + t] = Ww[t]; }
  __syncthreads();                   // the ONLY block barrier

  const int wv = t >> 6, l = t & 63;
  const int e16 = l & 15, ch = l >> 4;
  const int gw = blockIdx.x * WPB + wv;
  char* hw = hln[wv];

  float u0 = softplusf(craw[0]), u1 = softplusf(craw[1]), u2 = softplusf(craw[2]);
  float us = u0 + u1 + u2, c0 = u0 / us, c1 = u1 / us;
  float sc = sscale[0], sh = sshift[0], bp0 = bp[0], bw0 = bw[0], ww128 = Ww[128];

  for (int tile = gw; tile < NTILES; tile += NWAVES) {
    const int s0 = tile * 16;
    // ---- gathers: lane handles edge e16, chunks ch of nodes(2x16B) + nbrs(2x16B) each side ----
    int eg = s0 + e16;
    int es = ssrc[eg], ed = sdst[eg];
    float sxs = nscale[es], sxd = nscale[ed];
    const uint4* xp = (const uint4*)(qnodes + (size_t)es * CC);
    const uint4* yp = (const uint4*)(qnodes + (size_t)ed * CC);
    uint4 X0 = xp[ch], X1 = xp[4 + ch], Y0 = yp[ch], Y1 = yp[4 + ch];
    const uint4* nxp = (const uint4*)(qnbrs + (size_t)es * CC);
    const uint4* nyp = (const uint4*)(qnbrs + (size_t)ed * CC);
    uint4 NX0 = nxp[2 * ch], NX1 = nxp[2 * ch + 1];
    uint4 NY0 = nyp[2 * ch], NY1 = nyp[2 * ch + 1];
    float nbs = nbscale[es] * nbscale[ed];

    // ---- nbrs similarity ----
    int sa = 0;
    sa = sdot4i(NX0.x, NY0.x, sa); sa = sdot4i(NX0.y, NY0.y, sa);
    sa = sdot4i(NX0.z, NY0.z, sa); sa = sdot4i(NX0.w, NY0.w, sa);
    sa = sdot4i(NX1.x, NY1.x, sa); sa = sdot4i(NX1.y, NY1.y, sa);
    sa = sdot4i(NX1.z, NY1.z, sa); sa = sdot4i(NX1.w, NY1.w, sa);
    sa += __shfl_xor(sa, 16, 64); sa += __shfl_xor(sa, 32, 64);
    float nsim = (float)sa * nbs;

    unsigned xw[8] = {X0.x, X0.y, X0.z, X0.w, X1.x, X1.y, X1.z, X1.w};
    unsigned yw[8] = {Y0.x, Y0.y, Y0.z, Y0.w, Y1.x, Y1.y, Y1.z, Y1.w};

    // ---- pass 1: row amax of combined (a|m) over this edge ----
    float amax = 1e-8f;
#pragma unroll
    for (int d = 0; d < 8; d++)
#pragma unroll
      for (int b = 0; b < 4; b++) {
        float fx = (float)((int)(xw[d] << (24 - 8 * b)) >> 24) * sxs;
        float fy = (float)((int)(yw[d] << (24 - 8 * b)) >> 24) * sxd;
        amax = fmaxf(amax, fmaxf(fabsf(fx + fy), fabsf(fx * fy)));
      }
    amax = fmaxf(amax, __shfl_xor(amax, 16, 64));
    amax = fmaxf(amax, __shfl_xor(amax, 32, 64));
    float rqz = 127.f / amax, rsc = amax / 127.f;

    // ---- pass 2: build 4 int8 A-frags (ksteps: a0,a1,m0,m1) ----
    i32x4 fr[4];
#pragma unroll
    for (int half = 0; half < 2; half++) {
#pragma unroll
      for (int d = 0; d < 4; d++) {
        unsigned xd = xw[half * 4 + d], yd = yw[half * 4 + d];
        float a_[4], m_[4];
#pragma unroll
        for (int b = 0; b < 4; b++) {
          float fx = (float)((int)(xd << (24 - 8 * b)) >> 24) * sxs;
          float fy = (float)((int)(yd << (24 - 8 * b)) >> 24) * sxd;
          a_[b] = fx + fy; m_[b] = fx * fy;
        }
        fr[half][d]     = (int)pack4(a_[0] * rqz, a_[1] * rqz, a_[2] * rqz, a_[3] * rqz);
        fr[2 + half][d] = (int)pack4(m_[0] * rqz, m_[1] * rqz, m_[2] * rqz, m_[3] * rqz);
      }
    }
    float rsrow[4];
#pragma unroll
    for (int j = 0; j < 4; j++) rsrow[j] = __shfl(rsc, (ch << 2) + j, 64);

    // ---- GEMM1: i8 MFMA, weights from LDS ----
    i32x4 acc[16];
#pragma unroll
    for (int nf = 0; nf < 16; nf++) acc[nf] = (i32x4){0, 0, 0, 0};
#pragma unroll
    for (int s = 0; s < 4; s++) {
      int gofs = (((s * 4 + ch) ^ e16) << 4);
#pragma unroll
      for (int nf = 0; nf < 16; nf++) {
        i32x4 bfr = *(const i32x4*)&w0s[(nf * 16 + e16) * 256 + gofs];
        acc[nf] = __builtin_amdgcn_mfma_i32_16x16x64_i8(fr[s], bfr, acc[nf], 0, 0, 0);
      }
    }

    // ---- LN1 stats (in-register + 16-lane shuffles) ----
    float sj[4] = {0, 0, 0, 0}, qj[4] = {0, 0, 0, 0};
#pragma unroll
    for (int nf = 0; nf < 16; nf++) {
      float cs = prm[nf * 16 + e16], bb = prm[256 + nf * 16 + e16];
#pragma unroll
      for (int j = 0; j < 4; j++) {
        float h = (float)acc[nf][j] * rsrow[j] * cs + bb;
        sj[j] += h; qj[j] += h * h;
      }
    }
    float mu[4], rstd[4];
#pragma unroll
    for (int j = 0; j < 4; j++) {
      float s = sj[j], q = qj[j];
#pragma unroll
      for (int off = 1; off < 16; off <<= 1) { s += __shfl_xor(s, off, 64); q += __shfl_xor(q, off, 64); }
      mu[j] = s * (1.f / 256.f);
      rstd[j] = rsqrtf(q * (1.f / 256.f) - mu[j] * mu[j] + 1e-5f);
    }
    // ---- normalize + relu (store v into acc bits), track row max ----
    float hmax[4] = {1e-8f, 1e-8f, 1e-8f, 1e-8f};
#pragma unroll
    for (int nf = 0; nf < 16; nf++) {
      float cs = prm[nf * 16 + e16], bb = prm[256 + nf * 16 + e16];
      float gg = prm[512 + nf * 16 + e16], be = prm[768 + nf * 16 + e16];
#pragma unroll
      for (int j = 0; j < 4; j++) {
        float h = (float)acc[nf][j] * rsrow[j] * cs + bb;
        float v = fmaxf((h - mu[j]) * rstd[j] * gg + be, 0.f);
        hmax[j] = fmaxf(hmax[j], v);
        acc[nf][j] = __float_as_int(v);
      }
    }
    float rq2[4], rs2[4];
#pragma unroll
    for (int j = 0; j < 4; j++) {
      float m = hmax[j];
#pragma unroll
      for (int off = 1; off < 16; off <<= 1) m = fmaxf(m, __shfl_xor(m, off, 64));
      rq2[j] = 127.f / m; rs2[j] = m / 127.f;
    }
    // ---- write h_ln int8 to private LDS tile (swizzled) ----
#pragma unroll
    for (int nf = 0; nf < 16; nf++) {
#pragma unroll
      for (int j = 0; j < 4; j++) {
        int r = (ch << 2) + j;
        int qv = __float2int_rn(__int_as_float(acc[nf][j]) * rq2[j]);
        hw[r * 256 + ((nf ^ r) << 4) + e16] = (char)qv;
      }
    }

    // ---- GEMM2: i8 MFMA, A from private LDS, B from w1s ----
    i32x4 acc2[8];
#pragma unroll
    for (int nf = 0; nf < 8; nf++) acc2[nf] = (i32x4){0, 0, 0, 0};
#pragma unroll
    for (int s = 0; s < 4; s++) {
      int gofs = (((s * 4 + ch) ^ e16) << 4);
      i32x4 af = *(const i32x4*)&hw[e16 * 256 + gofs];
#pragma unroll
      for (int nf = 0; nf < 8; nf++) {
        i32x4 bfr = *(const i32x4*)&w1s[(nf * 16 + e16) * 256 + gofs];
        acc2[nf] = __builtin_amdgcn_mfma_i32_16x16x64_i8(af, bfr, acc2[nf], 0, 0, 0);
      }
    }

    // ---- LN2 + heads ----
    float s2[4] = {0, 0, 0, 0}, q2[4] = {0, 0, 0, 0};
#pragma unroll
    for (int nf = 0; nf < 8; nf++) {
      float cs = prm[1024 + nf * 16 + e16], bb = prm[1152 + nf * 16 + e16];
#pragma unroll
      for (int j = 0; j < 4; j++) {
        float ef = (float)acc2[nf][j] * rs2[j] * cs + bb;
        s2[j] += ef; q2[j] += ef * ef;
      }
    }
    float mu2[4], rstd2[4];
#pragma unroll
    for (int j = 0; j < 4; j++) {
      float s = s2[j], q = q2[j];
#pragma unroll
      for (int off = 1; off < 16; off <<= 1) { s += __shfl_xor(s, off, 64); q += __shfl_xor(q, off, 64); }
      mu2[j] = s * (1.f / 128.f);
      rstd2[j] = rsqrtf(q * (1.f / 128.f) - mu2[j] * mu2[j] + 1e-5f);
    }
    float pd[4] = {0, 0, 0, 0}, ws_[4] = {0, 0, 0, 0};
#pragma unroll
    for (int nf = 0; nf < 8; nf++) {
      float cs = prm[1024 + nf * 16 + e16], bb = prm[1152 + nf * 16 + e16];
      float gg = prm[1280 + nf * 16 + e16], be = prm[1408 + nf * 16 + e16];
      float wp_ = prm[1536 + nf * 16 + e16], ww_ = prm[1664 + nf * 16 + e16];
#pragma unroll
      for (int j = 0; j < 4; j++) {
        float ef = (float)acc2[nf][j] * rs2[j] * cs + bb;
        float v = fmaxf((ef - mu2[j]) * rstd2[j] * gg + be, 0.f);
        pd[j] += v * wp_; ws_[j] += v * ww_;
      }
    }
#pragma unroll
    for (int j = 0; j < 4; j++)
#pragma unroll
      for (int off = 1; off < 16; off <<= 1) {
        pd[j] += __shfl_xor(pd[j], off, 64);
        ws_[j] += __shfl_xor(ws_[j], off, 64);
      }
    float nsr[4];
#pragma unroll
    for (int j = 0; j < 4; j++) nsr[j] = __shfl(nsim, (ch << 2) + j, 64);
    if (e16 == 0) {
#pragma unroll
      for (int j = 0; j < 4; j++) {
        int sidx = s0 + (ch << 2) + j;
        out[3 * sidx + 0] = c0 * (pd[j] + bp0);
        out[3 * sidx + 1] = c1 * (sc * (nsr[j] + sh));
        out[3 * ESn + sidx] = fmaxf(ws_[j] + nsr[j] * ww128 + bw0, 0.f);
      }
    }
  }

  // ---- cos phase (all waves, after their MLP tiles) ----
  const int li8 = l & 7, grp = l >> 3;
  for (int i = gw; i < EMn / 8; i += NWAVES) {
    int e = i * 8 + grp;
    int q = qnode[md[e]];
    if (q < 0) continue;
    int s = ms[e];
    uint4 a = ((const uint4*)(qunit + (size_t)q * CC))[li8];
    uint4 b = ((const uint4*)(qunit + (size_t)s * CC))[li8];
    int acc = 0;
    acc = sdot4i(a.x, b.x, acc); acc = sdot4i(a.y, b.y, acc);
    acc = sdot4i(a.z, b.z, acc); acc = sdot4i(a.w, b.w, acc);
    acc += __shfl_xor(acc, 1, 64);
    acc += __shfl_xor(acc, 2, 64);
    acc += __shfl_xor(acc, 4, 64);
    if (li8 == 0) {
      float cv = (float)acc * (1.0f / (127.f * 127.f));
      float wvv = expf(10.0f * cv);
      atomicAdd(&dencnt[q], (double)wvv + 4294967296.0);   // den + cnt*2^32 packed
      atomicAdd(&num[q], wvv * cv);
    }
  }
}

} // namespace

extern "C" void kernel_launch(void* const* d_in, const int* in_sizes, int n_in,
                              void* d_out, int out_size, void* d_ws, size_t ws_size,
                              hipStream_t stream) {
  (void)in_sizes; (void)n_in; (void)out_size; (void)ws_size;
  const float* nodes  = (const float*)d_in[0];
  const float* nbrs   = (const float*)d_in[1];
  const int* sup_src  = (const int*)d_in[2];
  const int* sup_dst  = (const int*)d_in[3];
  const int* msg_src  = (const int*)d_in[4];
  const int* msg_dst  = (const int*)d_in[5];
  // d_in[6] message_edgestr: dead
  const float* W0  = (const float*)d_in[7];
  const float* b0  = (const float*)d_in[8];
  const float* g0  = (const float*)d_in[9];
  const float* be0 = (const float*)d_in[10];
  const float* W1  = (const float*)d_in[11];
  const float* b1  = (const float*)d_in[12];
  const float* g1  = (const float*)d_in[13];
  const float* be1 = (const float*)d_in[14];
  const float* Wp  = (const float*)d_in[15];
  const float* bp  = (const float*)d_in[16];
  const float* Ww  = (const float*)d_in[17];
  const float* bw  = (const float*)d_in[18];
  const float* sscale = (const float*)d_in[19];
  const float* sshift = (const float*)d_in[20];
  const float* craw   = (const float*)d_in[21];
  // d_in[22..27] mm_*: dead
  float* out = (float*)d_out;

  char* p = (char*)d_ws;
  auto take = [&](size_t bytes) -> char* {
    char* r = p; p += (bytes + 255) & ~(size_t)255; return r;
  };
  char*   w0q     = take((size_t)256 * 256);
  char*   w1q     = take((size_t)128 * 256);
  float*  cs0     = (float*)take((size_t)256 * 4);
  float*  cs1     = (float*)take((size_t)128 * 4);
  char*   qnodes  = take((size_t)NN * CC);
  char*   qunit   = take((size_t)NN * CC);
  char*   qnbrs   = take((size_t)NN * CC);
  float*  nscale  = (float*)take((size_t)NN * 4);
  float*  nbscale = (float*)take((size_t)NN * 4);
  int*    pidx    = (int*)take((size_t)NN * 4);
  int*    qnode   = (int*)take((size_t)NN * 4);
  double* dencnt  = (double*)take((size_t)NN * 8);
  float*  num     = (float*)take((size_t)NN * 4);
  float*  cong    = (float*)take((size_t)NN * 4);

  k_init<<<(NN + 255) / 256, 256, 0, stream>>>(pidx, dencnt, num);
  k_cvtq<<<(2 * NN + 15) / 16, 256, 0, stream>>>(nodes, nbrs, qnodes, qunit, qnbrs,
                                                 nscale, nbscale);
  k_prep2<<<384, 256, 0, stream>>>(W0, W1, w0q, w1q, cs0, cs1);
  k_partner<<<(2 * ESn + 255) / 256, 256, 0, stream>>>(sup_src, sup_dst, pidx);
  k_qnode<<<(NN + 255) / 256, 256, 0, stream>>>(pidx, sup_src, sup_dst, qnode);
  k_big<<<MLPB, 768, 0, stream>>>(qnodes, nscale, qnbrs, nbscale, qunit, qnode,
                                  sup_src, sup_dst, msg_src, msg_dst, dencnt, num,
                                  w0q, w1q, cs0, cs1, b0, g0, be0, b1, g1, be1,
                                  Wp, bp, Ww, bw, sscale, sshift, craw, out);
  k_cong<<<(NN + 255) / 256, 256, 0, stream>>>(dencnt, num, cong);
  k_finish<<<(ESn + 255) / 256, 256, 0, stream>>>(sup_src, sup_dst, cong,
                                                  sscale, sshift, craw, out);
}